// Round 7
// baseline (6379.233 us; speedup 1.0000x reference)
//
#include <hip/hip_runtime.h>

// LSTM T=512 B=256 NP=34 H=512 NT=16.
// 16 groups (16 batches) x 16 blocks (32 h-cols, all 4 gates).
// R10 = R8 skeleton with the exchange redesigned around poll-traffic:
//   * release-counter handshake: producer waves publish h u64s (relaxed
//     agent) then lane0 does fetch_add(cnt[t][g],1,RELEASE,agent); the
//     release fence guarantees data is at the coherence point first.
//   * consumer: ONE thread polls cnt[t-1][g] (4 B/round vs 16 KB/round ->
//     ~250x less LLC poll traffic, kills the congestion that set R8's
//     detection cadence), barrier, then a guaranteed-valid pipelined bulk
//     load (4x dwordx4 sc0 sc1, 64 B contiguous/thread, one waitcnt).
//   * no hs sentinel memset needed (validity from counters) -> 128 MB
//     memset off the timed stream; only 512 KB counters zeroed.
//   * W_hh fragments resident in REGISTERS (16x2 bf16x8 = 128 VGPR,
//     statically indexed): GEMM stops re-reading constant W from LDS
//     (was 2/3 of its LDS traffic at the 256 B/cy ceiling).
#define TT 512
#define BT 256
#define NP 34
#define HH 512

typedef short bf16x8 __attribute__((ext_vector_type(8)));
typedef float f32x4 __attribute__((ext_vector_type(4)));
typedef unsigned int u32x4 __attribute__((ext_vector_type(4)));

static __device__ __forceinline__ unsigned short f2bf(float x) {
  unsigned int u = __float_as_uint(x);
  return (unsigned short)((u + 0x7fffu + ((u >> 16) & 1u)) >> 16);
}

template <int CTRL>
static __device__ __forceinline__ float dppq(float x) {
  return __int_as_float(
      __builtin_amdgcn_mov_dpp(__float_as_int(x), CTRL, 0xF, 0xF, true));
}

static __device__ __forceinline__ float rcpf(float x) {
  return __builtin_amdgcn_rcpf(x);
}

// Guaranteed-valid bulk load: 64 B contiguous per thread, bypass to the
// coherence point (sc0 sc1), single waitcnt.
static __device__ __forceinline__ void bulk64(const unsigned long long* p,
                                              u32x4& b0, u32x4& b1,
                                              u32x4& b2, u32x4& b3) {
  asm volatile(
      "global_load_dwordx4 %0, %4, off sc0 sc1\n\t"
      "global_load_dwordx4 %1, %4, off offset:16 sc0 sc1\n\t"
      "global_load_dwordx4 %2, %4, off offset:32 sc0 sc1\n\t"
      "global_load_dwordx4 %3, %4, off offset:48 sc0 sc1\n\t"
      "s_waitcnt vmcnt(0)"
      : "=&v"(b0), "=&v"(b1), "=&v"(b2), "=&v"(b3)
      : "v"(p)
      : "memory");
}

// LDS (163840 B dynamic):
//   [0, 131072)        Whh slice bf16 [128 rows][512] (init only; fragments
//                      are extracted to registers, region dead afterwards)
//   [131072, 163840)   h-stage bf16 2 x [16][512] (16B-chunk swizzle
//                      phys_chunk = c ^ (r&7)), double-buffered by t parity.
__global__ void __launch_bounds__(256, 1) lstm_coop(
    const float* __restrict__ Whh, const float* __restrict__ Wih,
    const float* __restrict__ bih, const float* __restrict__ bhh,
    const unsigned short* __restrict__ Ax,  // [T][256][64] bf16: [points(34),0..]
    unsigned short* hs,                     // [T][256][512] bf16 (no pre-fill)
    unsigned* cnt)                          // [T][16] release counters, stride 16 u32, zeroed
{
  extern __shared__ char smem[];
  unsigned short* Wl = (unsigned short*)smem;
  unsigned short* stg = (unsigned short*)(smem + 131072);

  const int tid = threadIdx.x;
  const int g = blockIdx.x & 15;   // group
  const int n = blockIdx.x >> 4;   // h-col slice [n*32, n*32+32)
  const int bbase = g * 16;

  // ---- init Whh slice into LDS (swizzled, reordered rows r = j*4+q) ----
  for (int idx = tid; idx < 128 * 512; idx += 256) {
    int r = idx >> 9, k = idx & 511;
    int grow = (r & 3) * 512 + n * 32 + (r >> 2);
    float v = Whh[(size_t)grow * 512 + k];
    int c = k >> 3;
    Wl[r * 512 + ((c ^ (r & 7)) << 3) + (k & 7)] = f2bf(v);
  }

  const int lane = tid & 63;
  const int w = tid >> 6;        // wave: owns cols [8w, 8w+8) of this slice
  const int m = lane & 15;       // A row (batch) / B tile-row
  const int ko = lane >> 4;      // k-subgroup
  const int r0 = 32 * w + m;
  const int q = m & 3;           // gate owned by this lane
  const int jj = m >> 2;         // col-in-wave quad group
  const int j0 = 8 * w + jj;     // acc0 col (block-local)
  const int j1 = j0 + 4;         // acc1 col
  const int mx = m & 7;

  // biases for all 4 gates at cols j0, j1
  float bi0[4], bi1[4];
#pragma unroll
  for (int gg = 0; gg < 4; ++gg) {
    int gr0 = gg * 512 + n * 32 + j0;
    int gr1 = gg * 512 + n * 32 + j1;
    bi0[gg] = bih[gr0] + bhh[gr0];
    bi1[gg] = bih[gr1] + bhh[gr1];
  }

  // hoisted x-slice W fragments (constant over t), straight from global Wih
  bf16x8 bx0a, bx1a, bx0b, bx1b;
  {
    int grow0 = q * 512 + n * 32 + j0;   // row r0    -> (gate q, col j0)
    int grow1 = q * 512 + n * 32 + j1;   // row r0+16 -> (gate q, col j1)
#pragma unroll
    for (int e = 0; e < 8; ++e) {
      int ka = 8 * ko + e;        // [0,32) always < 34
      int kb = 32 + 8 * ko + e;   // valid only while < 34
      bx0a[e] = (short)f2bf(Wih[grow0 * 34 + ka]);
      bx1a[e] = (short)f2bf(Wih[grow1 * 34 + ka]);
      bx0b[e] = (kb < NP) ? (short)f2bf(Wih[grow0 * 34 + kb]) : (short)0;
      bx1b[e] = (kb < NP) ? (short)f2bf(Wih[grow1 * 34 + kb]) : (short)0;
    }
  }
  __syncthreads();  // Wl staged

  // ---- extract Whh fragments to registers (statically indexed) ----
  bf16x8 wv0[16], wv1[16];
#pragma unroll
  for (int s = 0; s < 16; ++s) {
    int cs = (((4 * s + ko) ^ mx) << 3);
    wv0[s] = *(const bf16x8*)&Wl[r0 * 512 + cs];
    wv1[s] = *(const bf16x8*)&Wl[(r0 + 16) * 512 + cs];
  }
  // Wl region is dead from here on.

  const bool q0 = (q == 0), q1 = (q == 1), q2 = (q == 2);
  float cc0 = 0.f, cc1 = 0.f;  // cell state for (batch 4ko+q, cols j0/j1)

  // prologue: x fragments for t=0
  bf16x8 xv0, xv1;
  {
    const unsigned short* xb = Ax + ((size_t)0 * BT + bbase + m) * 64;
    xv0 = *(const bf16x8*)(xb + (ko << 3));
    xv1 = *(const bf16x8*)(xb + 32 + (ko << 3));
  }

  for (int t = 0; t < TT; ++t) {
    // ---- acquire h(t-1): counter poll (1 thread) + guaranteed bulk load ----
    unsigned long long hv[8];
    if (t > 0) {
      if (tid == 0) {
        const unsigned* cp = cnt + (size_t)(t - 1) * 16 + g;  // (stride applied below)
        int guard = 0;
        for (;;) {
          unsigned v = __hip_atomic_load(cnt + ((size_t)(t - 1) * 16 + g) * 16,
                                         __ATOMIC_RELAXED,
                                         __HIP_MEMORY_SCOPE_AGENT);
          if (v >= 64u) break;
          if (++guard > (1 << 22)) break;  // deadlock guard
        }
        (void)cp;
      }
      __syncthreads();  // all threads held until counter shows full release
      const unsigned long long* hb =
          (const unsigned long long*)(hs + ((size_t)(t - 1) * BT + bbase) * HH) +
          (size_t)tid * 8;
      u32x4 b0, b1, b2, b3;
      bulk64(hb, b0, b1, b2, b3);
      hv[0] = ((unsigned long long)b0.y << 32) | b0.x;
      hv[1] = ((unsigned long long)b0.w << 32) | b0.z;
      hv[2] = ((unsigned long long)b1.y << 32) | b1.x;
      hv[3] = ((unsigned long long)b1.w << 32) | b1.z;
      hv[4] = ((unsigned long long)b2.y << 32) | b2.x;
      hv[5] = ((unsigned long long)b2.w << 32) | b2.z;
      hv[6] = ((unsigned long long)b3.y << 32) | b3.x;
      hv[7] = ((unsigned long long)b3.w << 32) | b3.z;
    } else {
#pragma unroll
      for (int u = 0; u < 8; ++u) hv[u] = 0ull;
    }

    // stage into LDS (swizzled), double-buffered by t parity.
    // idx = tid*8+u -> row mm=idx>>7, 8B unit cu=idx&127.
    unsigned short* st = stg + (t & 1) * 8192;
#pragma unroll
    for (int u = 0; u < 8; ++u) {
      int idx = tid * 8 + u;
      int mm = idx >> 7, cu = idx & 127;
      int c16 = cu >> 1, half = cu & 1;
      *(unsigned long long*)&st[mm * 512 + ((c16 ^ (mm & 7)) << 3) + (half << 2)] = hv[u];
    }
    __syncthreads();  // stage visible

    // ---- gates GEMM: h (K=512) from stage x register W, x tail, 4 chains ----
    f32x4 a0a = {0.f, 0.f, 0.f, 0.f}, a0b = {0.f, 0.f, 0.f, 0.f};
    f32x4 a1a = {0.f, 0.f, 0.f, 0.f}, a1b = {0.f, 0.f, 0.f, 0.f};
#pragma unroll
    for (int s = 0; s < 16; ++s) {
      int cs = (((4 * s + ko) ^ mx) << 3);
      bf16x8 av = *(const bf16x8*)&st[m * 512 + cs];
      if (s & 1) {
        a0b = __builtin_amdgcn_mfma_f32_16x16x32_bf16(av, wv0[s], a0b, 0, 0, 0);
        a1b = __builtin_amdgcn_mfma_f32_16x16x32_bf16(av, wv1[s], a1b, 0, 0, 0);
      } else {
        a0a = __builtin_amdgcn_mfma_f32_16x16x32_bf16(av, wv0[s], a0a, 0, 0, 0);
        a1a = __builtin_amdgcn_mfma_f32_16x16x32_bf16(av, wv1[s], a1a, 0, 0, 0);
      }
    }
    a0a = __builtin_amdgcn_mfma_f32_16x16x32_bf16(xv0, bx0a, a0a, 0, 0, 0);
    a1a = __builtin_amdgcn_mfma_f32_16x16x32_bf16(xv0, bx1a, a1a, 0, 0, 0);
    a0b = __builtin_amdgcn_mfma_f32_16x16x32_bf16(xv1, bx0b, a0b, 0, 0, 0);
    a1b = __builtin_amdgcn_mfma_f32_16x16x32_bf16(xv1, bx1b, a1b, 0, 0, 0);
    f32x4 A0 = a0a + a0b;
    f32x4 A1 = a1a + a1b;

    // ---- epilogue: quad gather (rot d brings lane(q+d)'s A[q]) ----
    float own0 = q0 ? A0.x : q1 ? A0.y : q2 ? A0.z : A0.w;
    float t1s0 = q0 ? A0.w : q1 ? A0.x : q2 ? A0.y : A0.z;
    float t2s0 = q0 ? A0.z : q1 ? A0.w : q2 ? A0.x : A0.y;
    float t3s0 = q0 ? A0.y : q1 ? A0.z : q2 ? A0.w : A0.x;
    float r1_0 = dppq<0x39>(t1s0);  // quad rot +1
    float r2_0 = dppq<0x4E>(t2s0);  // quad rot +2
    float r3_0 = dppq<0x93>(t3s0);  // quad rot +3
    float own1 = q0 ? A1.x : q1 ? A1.y : q2 ? A1.z : A1.w;
    float t1s1 = q0 ? A1.w : q1 ? A1.x : q2 ? A1.y : A1.z;
    float t2s1 = q0 ? A1.z : q1 ? A1.w : q2 ? A1.x : A1.y;
    float t3s1 = q0 ? A1.y : q1 ? A1.z : q2 ? A1.w : A1.x;
    float r1_1 = dppq<0x39>(t1s1);
    float r2_1 = dppq<0x4E>(t2s1);
    float r3_1 = dppq<0x93>(t3s1);
    float gi0 = (q0 ? own0 : q1 ? r3_0 : q2 ? r2_0 : r1_0) + bi0[0];
    float gf0 = (q0 ? r1_0 : q1 ? own0 : q2 ? r3_0 : r2_0) + bi0[1];
    float gg0 = (q0 ? r2_0 : q1 ? r1_0 : q2 ? own0 : r3_0) + bi0[2];
    float go0 = (q0 ? r3_0 : q1 ? r2_0 : q2 ? r1_0 : own0) + bi0[3];
    float gi1 = (q0 ? own1 : q1 ? r3_1 : q2 ? r2_1 : r1_1) + bi1[0];
    float gf1 = (q0 ? r1_1 : q1 ? own1 : q2 ? r3_1 : r2_1) + bi1[1];
    float gg1 = (q0 ? r2_1 : q1 ? r1_1 : q2 ? own1 : r3_1) + bi1[2];
    float go1 = (q0 ? r3_1 : q1 ? r2_1 : q2 ? r1_1 : own1) + bi1[3];

    float ii0 = rcpf(1.f + __expf(-gi0));
    float ff0 = rcpf(1.f + __expf(-gf0));
    float tg0 = 2.f * rcpf(1.f + __expf(-2.f * gg0)) - 1.f;
    float oo0 = rcpf(1.f + __expf(-go0));
    cc0 = ff0 * cc0 + ii0 * tg0;
    float h0 = oo0 * (2.f * rcpf(1.f + __expf(-2.f * cc0)) - 1.f);

    float ii1 = rcpf(1.f + __expf(-gi1));
    float ff1 = rcpf(1.f + __expf(-gf1));
    float tg1 = 2.f * rcpf(1.f + __expf(-2.f * gg1)) - 1.f;
    float oo1 = rcpf(1.f + __expf(-go1));
    cc1 = ff1 * cc1 + ii1 * tg1;
    float h1 = oo1 * (2.f * rcpf(1.f + __expf(-2.f * cc1)) - 1.f);

    // ---- publish h(t): pack 4 cols per u64, relaxed agent stores ----
    float h0p = __shfl_xor(h0, 4);
    float h1p = __shfl_xor(h1, 4);
    unsigned p0 = (unsigned)f2bf(h0) | ((unsigned)f2bf(h0p) << 16);
    unsigned p1 = (unsigned)f2bf(h1) | ((unsigned)f2bf(h1p) << 16);
    unsigned s0 = (unsigned)__shfl_xor((int)p0, 8);
    unsigned s1 = (unsigned)__shfl_xor((int)p1, 8);
    if (!(jj & 1)) {
      unsigned long long val = (jj == 0)
          ? (((unsigned long long)s0 << 32) | p0)    // cols 8w..8w+3
          : (((unsigned long long)p1 << 32) | s1);   // cols 8w+4..8w+7
      size_t uidx = ((size_t)t * BT + bbase + 4 * ko + q) * 128 +
                    8 * n + 2 * w + (jj >> 1);
      __hip_atomic_store((unsigned long long*)hs + uidx, val,
                         __ATOMIC_RELAXED, __HIP_MEMORY_SCOPE_AGENT);
    }
    // ---- release signal: one add per wave; release fence orders the
    // wave's data stores to the coherence point before the increment.
    if (lane == 0) {
      __hip_atomic_fetch_add(cnt + ((size_t)t * 16 + g) * 16, 1u,
                             __ATOMIC_RELEASE, __HIP_MEMORY_SCOPE_AGENT);
    }
    // prefetch next step's x fragments (off the critical path)
    {
      int tn = (t + 1 < TT) ? t + 1 : t;
      const unsigned short* xb = Ax + ((size_t)tn * BT + bbase + m) * 64;
      xv0 = *(const bf16x8*)(xb + (ko << 3));
      xv1 = *(const bf16x8*)(xb + 32 + (ko << 3));
    }
  }
}

// Ax[t][b][k] = bf16(points[t][b][k]) for k<34 else 0
__global__ void __launch_bounds__(256) prep_ax(const float* __restrict__ pts,
                                               unsigned short* __restrict__ Ax) {
  size_t i = (size_t)blockIdx.x * 256 + threadIdx.x;  // [0, 512*256*64)
  int k = (int)(i & 63);
  size_t tb = i >> 6;
  float v = (k < NP) ? pts[tb * NP + k] : 0.f;
  Ax[i] = f2bf(v);
}

// logits = hs @ W_lin^T + b_lin ; softmax over 16
__global__ void __launch_bounds__(256) head_kernel(const unsigned short* __restrict__ hs,
                                                   const float* __restrict__ Wlin,
                                                   const float* __restrict__ blin,
                                                   float* __restrict__ out) {
  __shared__ float wl[16 * 513];
  __shared__ float bl[16];
  __shared__ unsigned short hl[16 * 520];
  const int tid = threadIdx.x;
  for (int i = tid; i < 16 * 512; i += 256) wl[(i >> 9) * 513 + (i & 511)] = Wlin[i];
  if (tid < 16) bl[tid] = blin[tid];
  const size_t Rb = (size_t)blockIdx.x * 16;  // 16 rows of [131072][512]
  const uint4* gsrc = (const uint4*)(hs + Rb * 512);
#pragma unroll
  for (int j = 0; j < 4; ++j) {
    int e8 = tid + 256 * j;  // uint4 index, 8 bf16 each
    uint4 v = gsrc[e8];
    int r = e8 >> 6, k = (e8 & 63) << 3;
    *(uint4*)&hl[r * 520 + k] = v;
  }
  __syncthreads();
  const int r = tid >> 4, tg = tid & 15;
  float acc = bl[tg];
  const float* wp = &wl[tg * 513];
#pragma unroll 4
  for (int k8 = 0; k8 < 64; ++k8) {
    uint4 hv = *(const uint4*)&hl[r * 520 + (k8 << 3)];
    const float* w8 = wp + (k8 << 3);
    acc += __uint_as_float(hv.x << 16) * w8[0];
    acc += __uint_as_float(hv.x & 0xffff0000u) * w8[1];
    acc += __uint_as_float(hv.y << 16) * w8[2];
    acc += __uint_as_float(hv.y & 0xffff0000u) * w8[3];
    acc += __uint_as_float(hv.z << 16) * w8[4];
    acc += __uint_as_float(hv.z & 0xffff0000u) * w8[5];
    acc += __uint_as_float(hv.w << 16) * w8[6];
    acc += __uint_as_float(hv.w & 0xffff0000u) * w8[7];
  }
  float mx = acc;
#pragma unroll
  for (int d = 8; d; d >>= 1) mx = fmaxf(mx, __shfl_xor(mx, d, 16));
  float e = __expf(acc - mx);
  float sm = e;
#pragma unroll
  for (int d = 8; d; d >>= 1) sm += __shfl_xor(sm, d, 16);
  out[Rb * 16 + tid] = e / sm;
}

extern "C" void kernel_launch(void* const* d_in, const int* in_sizes, int n_in,
                              void* d_out, int out_size, void* d_ws, size_t ws_size,
                              hipStream_t stream) {
  (void)in_sizes; (void)n_in; (void)out_size; (void)ws_size;
  const float* pts  = (const float*)d_in[0];
  const float* Wih  = (const float*)d_in[1];
  const float* Whh  = (const float*)d_in[2];
  const float* bih  = (const float*)d_in[3];
  const float* bhh  = (const float*)d_in[4];
  const float* Wlin = (const float*)d_in[5];
  const float* blin = (const float*)d_in[6];
  float* out = (float*)d_out;
  char* ws = (char*)d_ws;
  // ws layout: hs 134217728 | Ax 16777216 | cnt 524288
  unsigned short* hs = (unsigned short*)ws;
  unsigned short* Ax = (unsigned short*)(ws + 134217728);
  unsigned* cnt      = (unsigned*)(ws + 134217728 + 16777216);

  // only the counters need zeroing (hs validity comes from the release counters)
  hipMemsetAsync(cnt, 0, 524288, stream);
  prep_ax<<<32768, 256, 0, stream>>>(pts, Ax);
  (void)hipFuncSetAttribute((const void*)lstm_coop,
                            hipFuncAttributeMaxDynamicSharedMemorySize, 163840);
  void* args[7];
  args[0] = (void*)&Whh; args[1] = (void*)&Wih; args[2] = (void*)&bih;
  args[3] = (void*)&bhh; args[4] = (void*)&Ax;  args[5] = (void*)&hs;
  args[6] = (void*)&cnt;
  hipLaunchCooperativeKernel((void*)lstm_coop, dim3(256), dim3(256), args, 163840, stream);
  head_kernel<<<8192, 256, 0, stream>>>(hs, Wlin, blin, out);
}

// Round 10
// 1565.185 us; speedup vs baseline: 4.0757x; 4.0757x over previous
//
#include <hip/hip_runtime.h>

// LSTM T=512 B=256 NP=34 H=512 NT=16.
// 16 groups (16 batches) x 16 blocks (32 h-cols, all 4 gates).
// R12 = R8 (proven: sentinel protocol, pipelined vmcnt(0) poll rounds, u64
// publish, x-prefetch) + same-XCD L2 fast exchange, properly gated:
//   * probe phase (R7-proven): blocks read HW_REG_XCC_ID, rank (xcc,bid),
//     g=rank>>4, n=rank&15 -> each group's 16 blocks share one XCD exactly
//     (256 blocks, 1/CU, 32 CUs/XCD -> 32 ranks per XCD, no straddle).
//   * producers dual-publish each h u64: PLAIN store to hsF (write-through
//     L1 -> shared XCD L2) + relaxed agent store to hs (coherent anywhere).
//   * consumers first poll hsF with sc0-ONLY loads (L1-bypass, L2-served,
//     ~250cy rounds vs ~900cy LLC rounds); NON-POISONING gate: miss shrinks
//     next step's window to 2 rounds, full window retried every 16 steps.
//     Agent-scope sentinel poll of hs always finishes the step -> never-wrong.
//   * R11 lesson applied: every wait is vmcnt(0) INSIDE one asm block
//     (counted vmcnt across blocks is unsound when the compiler spills).
#define TT 512
#define BT 256
#define NP 34
#define HH 512
#define SENT 0xAAAAAAAAu

typedef short bf16x8 __attribute__((ext_vector_type(8)));
typedef float f32x4 __attribute__((ext_vector_type(4)));

static __device__ __forceinline__ unsigned short f2bf(float x) {
  unsigned int u = __float_as_uint(x);
  return (unsigned short)((u + 0x7fffu + ((u >> 16) & 1u)) >> 16);
}

template <int CTRL>
static __device__ __forceinline__ float dppq(float x) {
  return __int_as_float(
      __builtin_amdgcn_mov_dpp(__float_as_int(x), CTRL, 0xF, 0xF, true));
}

static __device__ __forceinline__ float rcpf(float x) {
  return __builtin_amdgcn_rcpf(x);
}

// One L2 poll round: 8 pipelined sc0-only u64 loads (L1-bypass, served by
// the XCD's L2), single vmcnt(0).
static __device__ __forceinline__ void load8_l2(const unsigned long long* p,
                                                unsigned long long o[8]) {
  asm volatile(
      "global_load_dwordx2 %0, %8, off sc0\n\t"
      "global_load_dwordx2 %1, %9, off sc0\n\t"
      "global_load_dwordx2 %2, %10, off sc0\n\t"
      "global_load_dwordx2 %3, %11, off sc0\n\t"
      "global_load_dwordx2 %4, %12, off sc0\n\t"
      "global_load_dwordx2 %5, %13, off sc0\n\t"
      "global_load_dwordx2 %6, %14, off sc0\n\t"
      "global_load_dwordx2 %7, %15, off sc0\n\t"
      "s_waitcnt vmcnt(0)"
      : "=&v"(o[0]), "=&v"(o[1]), "=&v"(o[2]), "=&v"(o[3]),
        "=&v"(o[4]), "=&v"(o[5]), "=&v"(o[6]), "=&v"(o[7])
      : "v"(p), "v"(p + 256), "v"(p + 512), "v"(p + 768),
        "v"(p + 1024), "v"(p + 1280), "v"(p + 1536), "v"(p + 1792)
      : "memory");
}

// One LLC poll round: 8 pipelined coherence-point loads, single vmcnt(0).
static __device__ __forceinline__ void load8_coh(const unsigned long long* p,
                                                 unsigned long long o[8]) {
  asm volatile(
      "global_load_dwordx2 %0, %8, off sc0 sc1\n\t"
      "global_load_dwordx2 %1, %9, off sc0 sc1\n\t"
      "global_load_dwordx2 %2, %10, off sc0 sc1\n\t"
      "global_load_dwordx2 %3, %11, off sc0 sc1\n\t"
      "global_load_dwordx2 %4, %12, off sc0 sc1\n\t"
      "global_load_dwordx2 %5, %13, off sc0 sc1\n\t"
      "global_load_dwordx2 %6, %14, off sc0 sc1\n\t"
      "global_load_dwordx2 %7, %15, off sc0 sc1\n\t"
      "s_waitcnt vmcnt(0)"
      : "=&v"(o[0]), "=&v"(o[1]), "=&v"(o[2]), "=&v"(o[3]),
        "=&v"(o[4]), "=&v"(o[5]), "=&v"(o[6]), "=&v"(o[7])
      : "v"(p), "v"(p + 256), "v"(p + 512), "v"(p + 768),
        "v"(p + 1024), "v"(p + 1280), "v"(p + 1536), "v"(p + 1792)
      : "memory");
}

static __device__ __forceinline__ unsigned validmask8(
    const unsigned long long o[8]) {
  unsigned ok = 1u;
#pragma unroll
  for (int u = 0; u < 8; ++u) {
    unsigned long long x = o[u];
    ok &= (((unsigned)x != SENT) & ((unsigned)(x >> 32) != SENT)) ? 1u : 0u;
  }
  return ok;
}

// LDS (163840 B dynamic):
//   [0, 131072)        Whh slice bf16 [128 rows][512], 16B-chunk swizzle
//                      phys_chunk = c ^ (r&7). Row r = j*4 + q (j=col, q=gate).
//   [131072, 163840)   probe keys (1 KB, once) then h-stage bf16 2x[16][512]
//                      (same swizzle), double-buffered by t parity.
__global__ void __launch_bounds__(256, 1) lstm_coop(
    const float* __restrict__ Whh, const float* __restrict__ Wih,
    const float* __restrict__ bih, const float* __restrict__ bhh,
    const unsigned short* __restrict__ Ax,  // [T][256][64] bf16: [points(34),0..]
    unsigned short* hs,                     // [T][256][512] bf16, pre-SENT (agent)
    unsigned short* hsF,                    // same layout, pre-SENT (L2 fast path)
    unsigned* probe,                        // [256], pre-SENT
    int fastEn)
{
  extern __shared__ char smem[];
  unsigned short* Wl = (unsigned short*)smem;
  unsigned short* stg = (unsigned short*)(smem + 131072);

  const int tid = threadIdx.x;
  const int bid = blockIdx.x;

  // ---- probe phase: runtime block->XCD discovery, deterministic ranking ----
  int g, n;
  if (fastEn) {
    unsigned xcc;
    asm volatile("s_getreg_b32 %0, hwreg(HW_REG_XCC_ID)" : "=s"(xcc));
    if (tid == 0)
      __hip_atomic_store(probe + bid, (xcc & 255u) + 1u, __ATOMIC_RELAXED,
                         __HIP_MEMORY_SCOPE_AGENT);
    unsigned* keysL = (unsigned*)stg;
    unsigned v;
    int guard = 0;
    for (;;) {  // thread tid polls block tid's entry (co-residency guaranteed)
      v = __hip_atomic_load(probe + tid, __ATOMIC_RELAXED,
                            __HIP_MEMORY_SCOPE_AGENT);
      if (v != SENT) break;
      if (++guard > (1 << 24)) { v = 1; break; }
      __builtin_amdgcn_s_sleep(2);
    }
    keysL[tid] = (((v - 1u) & 255u) << 8) | (unsigned)tid;
    __syncthreads();
    unsigned mykey = keysL[bid];
    int rank = 0;
    for (int b = 0; b < 256; ++b) rank += (keysL[b] < mykey) ? 1 : 0;
    g = rank >> 4;   // group: 16 consecutive ranks -> same XCD
    n = rank & 15;   // h-col slice within group
    __syncthreads();  // keysL region reused as h-stage below
  } else {
    g = bid & 15;
    n = bid >> 4;
  }
  const int bbase = g * 16;

  // ---- init resident Whh slice (swizzled, reordered rows r = j*4+q) ----
  for (int idx = tid; idx < 128 * 512; idx += 256) {
    int r = idx >> 9, k = idx & 511;
    int grow = (r & 3) * 512 + n * 32 + (r >> 2);
    float v = Whh[(size_t)grow * 512 + k];
    int c = k >> 3;
    Wl[r * 512 + ((c ^ (r & 7)) << 3) + (k & 7)] = f2bf(v);
  }

  const int lane = tid & 63;
  const int w = tid >> 6;        // wave: owns cols [8w, 8w+8) of this slice
  const int m = lane & 15;       // A row (batch) / B tile-row
  const int ko = lane >> 4;      // k-subgroup
  const int r0 = 32 * w + m;
  const int q = m & 3;           // gate owned by this lane
  const int jj = m >> 2;         // col-in-wave quad group
  const int j0 = 8 * w + jj;     // acc0 col (block-local)
  const int j1 = j0 + 4;         // acc1 col
  const int mx = m & 7;

  // biases for all 4 gates at cols j0, j1
  float bi0[4], bi1[4];
#pragma unroll
  for (int gg = 0; gg < 4; ++gg) {
    int gr0 = gg * 512 + n * 32 + j0;
    int gr1 = gg * 512 + n * 32 + j1;
    bi0[gg] = bih[gr0] + bhh[gr0];
    bi1[gg] = bih[gr1] + bhh[gr1];
  }

  // hoisted x-slice W fragments (constant over t), straight from global Wih
  bf16x8 bx0a, bx1a, bx0b, bx1b;
  {
    int grow0 = q * 512 + n * 32 + j0;   // row r0    -> (gate q, col j0)
    int grow1 = q * 512 + n * 32 + j1;   // row r0+16 -> (gate q, col j1)
#pragma unroll
    for (int e = 0; e < 8; ++e) {
      int ka = 8 * ko + e;        // [0,32) always < 34
      int kb = 32 + 8 * ko + e;   // valid only while < 34
      bx0a[e] = (short)f2bf(Wih[grow0 * 34 + ka]);
      bx1a[e] = (short)f2bf(Wih[grow1 * 34 + ka]);
      bx0b[e] = (kb < NP) ? (short)f2bf(Wih[grow0 * 34 + kb]) : (short)0;
      bx1b[e] = (kb < NP) ? (short)f2bf(Wih[grow1 * 34 + kb]) : (short)0;
    }
  }
  __syncthreads();  // Wl ready (read-only hereafter)

  const bool q0 = (q == 0), q1 = (q == 1), q2 = (q == 2);
  float cc0 = 0.f, cc1 = 0.f;  // cell state for (batch 4ko+q, cols j0/j1)
  bool fastok = true;          // non-poisoning adaptive window

  // prologue: x fragments for t=0
  bf16x8 xv0, xv1;
  {
    const unsigned short* xb = Ax + ((size_t)0 * BT + bbase + m) * 64;
    xv0 = *(const bf16x8*)(xb + (ko << 3));
    xv1 = *(const bf16x8*)(xb + 32 + (ko << 3));
  }

  for (int t = 0; t < TT; ++t) {
    // ---- acquire h(t-1): same-XCD L2 fast poll, then LLC fallback ----
    unsigned long long hv[8];
    if (t > 0) {
      const size_t base = ((size_t)(t - 1) * BT + bbase) * 128;  // u64 units
      const unsigned long long* pF = (const unsigned long long*)hsF + base + tid;
      const unsigned long long* pb = (const unsigned long long*)hs + base + tid;
      unsigned ok = 0;
      // full window normally; after a miss shrink to 2, retry full every 16
      int tries = fastEn ? ((fastok || (t & 15) == 0) ? 64 : 2) : 0;
      for (int rr = 0; rr < tries; ++rr) {
        load8_l2(pF, hv);
        if ((ok = validmask8(hv)) != 0u) break;
      }
      fastok = (ok != 0u);
      if (!ok) {
        int guard = 0;
        for (;;) {  // correctness path: LLC sentinel poll (R8-proven)
          load8_coh(pb, hv);
          if (validmask8(hv)) break;
          if (++guard > (1 << 18)) break;  // deadlock guard
        }
      }
    } else {
#pragma unroll
      for (int u = 0; u < 8; ++u) hv[u] = 0ull;
    }

    // prefetch next step's x fragments (consumed at END of next GEMM)
    bf16x8 xn0, xn1;
    {
      int tn = (t + 1 < TT) ? t + 1 : t;
      const unsigned short* xb = Ax + ((size_t)tn * BT + bbase + m) * 64;
      xn0 = *(const bf16x8*)(xb + (ko << 3));
      xn1 = *(const bf16x8*)(xb + 32 + (ko << 3));
    }

    // stage into LDS (swizzled), double-buffered by t parity
    unsigned short* st = stg + (t & 1) * 8192;
#pragma unroll
    for (int u = 0; u < 8; ++u) {
      int idx = u * 256 + tid;           // [0,2048) 8B units
      int mm = idx >> 7, cu = idx & 127; // row, 8B unit in row
      int c16 = cu >> 1, half = cu & 1;
      *(unsigned long long*)&st[mm * 512 + ((c16 ^ (mm & 7)) << 3) + (half << 2)] = hv[u];
    }
    __syncthreads();  // the only per-step barrier: stage visible

    // ---- gates GEMM: h (K=512) then x (K=64) at the end, 4 acc chains ----
    f32x4 a0a = {0.f, 0.f, 0.f, 0.f}, a0b = {0.f, 0.f, 0.f, 0.f};
    f32x4 a1a = {0.f, 0.f, 0.f, 0.f}, a1b = {0.f, 0.f, 0.f, 0.f};
#pragma unroll
    for (int s = 0; s < 16; ++s) {
      int cs = (((4 * s + ko) ^ mx) << 3);
      bf16x8 av = *(const bf16x8*)&st[m * 512 + cs];
      bf16x8 bv0 = *(const bf16x8*)&Wl[r0 * 512 + cs];
      bf16x8 bv1 = *(const bf16x8*)&Wl[(r0 + 16) * 512 + cs];
      if (s & 1) {
        a0b = __builtin_amdgcn_mfma_f32_16x16x32_bf16(av, bv0, a0b, 0, 0, 0);
        a1b = __builtin_amdgcn_mfma_f32_16x16x32_bf16(av, bv1, a1b, 0, 0, 0);
      } else {
        a0a = __builtin_amdgcn_mfma_f32_16x16x32_bf16(av, bv0, a0a, 0, 0, 0);
        a1a = __builtin_amdgcn_mfma_f32_16x16x32_bf16(av, bv1, a1a, 0, 0, 0);
      }
    }
    a0a = __builtin_amdgcn_mfma_f32_16x16x32_bf16(xv0, bx0a, a0a, 0, 0, 0);
    a1a = __builtin_amdgcn_mfma_f32_16x16x32_bf16(xv0, bx1a, a1a, 0, 0, 0);
    a0b = __builtin_amdgcn_mfma_f32_16x16x32_bf16(xv1, bx0b, a0b, 0, 0, 0);
    a1b = __builtin_amdgcn_mfma_f32_16x16x32_bf16(xv1, bx1b, a1b, 0, 0, 0);
    f32x4 A0 = a0a + a0b;
    f32x4 A1 = a1a + a1b;

    // ---- epilogue: quad gather (rot d brings lane(q+d)'s A[q]) ----
    float own0 = q0 ? A0.x : q1 ? A0.y : q2 ? A0.z : A0.w;
    float t1s0 = q0 ? A0.w : q1 ? A0.x : q2 ? A0.y : A0.z;
    float t2s0 = q0 ? A0.z : q1 ? A0.w : q2 ? A0.x : A0.y;
    float t3s0 = q0 ? A0.y : q1 ? A0.z : q2 ? A0.w : A0.x;
    float r1_0 = dppq<0x39>(t1s0);  // quad rot +1
    float r2_0 = dppq<0x4E>(t2s0);  // quad rot +2
    float r3_0 = dppq<0x93>(t3s0);  // quad rot +3
    float own1 = q0 ? A1.x : q1 ? A1.y : q2 ? A1.z : A1.w;
    float t1s1 = q0 ? A1.w : q1 ? A1.x : q2 ? A1.y : A1.z;
    float t2s1 = q0 ? A1.z : q1 ? A1.w : q2 ? A1.x : A1.y;
    float t3s1 = q0 ? A1.y : q1 ? A1.z : q2 ? A1.w : A1.x;
    float r1_1 = dppq<0x39>(t1s1);
    float r2_1 = dppq<0x4E>(t2s1);
    float r3_1 = dppq<0x93>(t3s1);
    float gi0 = (q0 ? own0 : q1 ? r3_0 : q2 ? r2_0 : r1_0) + bi0[0];
    float gf0 = (q0 ? r1_0 : q1 ? own0 : q2 ? r3_0 : r2_0) + bi0[1];
    float gg0 = (q0 ? r2_0 : q1 ? r1_0 : q2 ? own0 : r3_0) + bi0[2];
    float go0 = (q0 ? r3_0 : q1 ? r2_0 : q2 ? r1_0 : own0) + bi0[3];
    float gi1 = (q0 ? own1 : q1 ? r3_1 : q2 ? r2_1 : r1_1) + bi1[0];
    float gf1 = (q0 ? r1_1 : q1 ? own1 : q2 ? r3_1 : r2_1) + bi1[1];
    float gg1 = (q0 ? r2_1 : q1 ? r1_1 : q2 ? own1 : r3_1) + bi1[2];
    float go1 = (q0 ? r3_1 : q1 ? r2_1 : q2 ? r1_1 : own1) + bi1[3];

    float ii0 = rcpf(1.f + __expf(-gi0));
    float ff0 = rcpf(1.f + __expf(-gf0));
    float tg0 = 2.f * rcpf(1.f + __expf(-2.f * gg0)) - 1.f;
    float oo0 = rcpf(1.f + __expf(-go0));
    cc0 = ff0 * cc0 + ii0 * tg0;
    float h0 = oo0 * (2.f * rcpf(1.f + __expf(-2.f * cc0)) - 1.f);

    float ii1 = rcpf(1.f + __expf(-gi1));
    float ff1 = rcpf(1.f + __expf(-gf1));
    float tg1 = 2.f * rcpf(1.f + __expf(-2.f * gg1)) - 1.f;
    float oo1 = rcpf(1.f + __expf(-go1));
    cc1 = ff1 * cc1 + ii1 * tg1;
    float h1 = oo1 * (2.f * rcpf(1.f + __expf(-2.f * cc1)) - 1.f);

    // pack 4 consecutive cols into one u64 per storing lane; dual publish:
    // plain store -> shared XCD L2 (fast path), agent store -> coherent hs.
    float h0p = __shfl_xor(h0, 4);
    float h1p = __shfl_xor(h1, 4);
    unsigned p0 = (unsigned)f2bf(h0) | ((unsigned)f2bf(h0p) << 16);
    unsigned p1 = (unsigned)f2bf(h1) | ((unsigned)f2bf(h1p) << 16);
    unsigned s0 = (unsigned)__shfl_xor((int)p0, 8);
    unsigned s1 = (unsigned)__shfl_xor((int)p1, 8);
    if (!(jj & 1)) {
      unsigned long long val = (jj == 0)
          ? (((unsigned long long)s0 << 32) | p0)    // cols 8w..8w+3
          : (((unsigned long long)p1 << 32) | s1);   // cols 8w+4..8w+7
      size_t uidx = ((size_t)t * BT + bbase + 4 * ko + q) * 128 +
                    8 * n + 2 * w + (jj >> 1);
      if (fastEn) {
        unsigned long long* pf = (unsigned long long*)hsF + uidx;
        asm volatile("global_store_dwordx2 %0, %1, off"
                     :: "v"(pf), "v"(val) : "memory");
      }
      __hip_atomic_store((unsigned long long*)hs + uidx, val,
                         __ATOMIC_RELAXED, __HIP_MEMORY_SCOPE_AGENT);
    }
    xv0 = xn0;
    xv1 = xn1;
  }
}

// Ax[t][b][k] = bf16(points[t][b][k]) for k<34 else 0
__global__ void __launch_bounds__(256) prep_ax(const float* __restrict__ pts,
                                               unsigned short* __restrict__ Ax) {
  size_t i = (size_t)blockIdx.x * 256 + threadIdx.x;  // [0, 512*256*64)
  int k = (int)(i & 63);
  size_t tb = i >> 6;
  float v = (k < NP) ? pts[tb * NP + k] : 0.f;
  Ax[i] = f2bf(v);
}

// logits = hs @ W_lin^T + b_lin ; softmax over 16
__global__ void __launch_bounds__(256) head_kernel(const unsigned short* __restrict__ hs,
                                                   const float* __restrict__ Wlin,
                                                   const float* __restrict__ blin,
                                                   float* __restrict__ out) {
  __shared__ float wl[16 * 513];
  __shared__ float bl[16];
  __shared__ unsigned short hl[16 * 520];
  const int tid = threadIdx.x;
  for (int i = tid; i < 16 * 512; i += 256) wl[(i >> 9) * 513 + (i & 511)] = Wlin[i];
  if (tid < 16) bl[tid] = blin[tid];
  const size_t Rb = (size_t)blockIdx.x * 16;  // 16 rows of [131072][512]
  const uint4* gsrc = (const uint4*)(hs + Rb * 512);
#pragma unroll
  for (int j = 0; j < 4; ++j) {
    int e8 = tid + 256 * j;  // uint4 index, 8 bf16 each
    uint4 v = gsrc[e8];
    int r = e8 >> 6, k = (e8 & 63) << 3;
    *(uint4*)&hl[r * 520 + k] = v;
  }
  __syncthreads();
  const int r = tid >> 4, tg = tid & 15;
  float acc = bl[tg];
  const float* wp = &wl[tg * 513];
#pragma unroll 4
  for (int k8 = 0; k8 < 64; ++k8) {
    uint4 hv = *(const uint4*)&hl[r * 520 + (k8 << 3)];
    const float* w8 = wp + (k8 << 3);
    acc += __uint_as_float(hv.x << 16) * w8[0];
    acc += __uint_as_float(hv.x & 0xffff0000u) * w8[1];
    acc += __uint_as_float(hv.y << 16) * w8[2];
    acc += __uint_as_float(hv.y & 0xffff0000u) * w8[3];
    acc += __uint_as_float(hv.z << 16) * w8[4];
    acc += __uint_as_float(hv.z & 0xffff0000u) * w8[5];
    acc += __uint_as_float(hv.w << 16) * w8[6];
    acc += __uint_as_float(hv.w & 0xffff0000u) * w8[7];
  }
  float mx = acc;
#pragma unroll
  for (int d = 8; d; d >>= 1) mx = fmaxf(mx, __shfl_xor(mx, d, 16));
  float e = __expf(acc - mx);
  float sm = e;
#pragma unroll
  for (int d = 8; d; d >>= 1) sm += __shfl_xor(sm, d, 16);
  out[Rb * 16 + tid] = e / sm;
}

extern "C" void kernel_launch(void* const* d_in, const int* in_sizes, int n_in,
                              void* d_out, int out_size, void* d_ws, size_t ws_size,
                              hipStream_t stream) {
  (void)in_sizes; (void)n_in; (void)out_size;
  const float* pts  = (const float*)d_in[0];
  const float* Wih  = (const float*)d_in[1];
  const float* Whh  = (const float*)d_in[2];
  const float* bih  = (const float*)d_in[3];
  const float* bhh  = (const float*)d_in[4];
  const float* Wlin = (const float*)d_in[5];
  const float* blin = (const float*)d_in[6];
  float* out = (float*)d_out;
  char* ws = (char*)d_ws;
  // ws layout (FAST): hs 134217728 | hsF 134217728 | Ax 16777216 | probe 4096
  const int FAST = (ws_size >= 285216768u) ? 1 : 0;
  unsigned short* hs  = (unsigned short*)ws;
  unsigned short* hsF = FAST ? (unsigned short*)(ws + 134217728) : hs;
  unsigned short* Ax  = (unsigned short*)(ws + (FAST ? 268435456 : 134217728));
  unsigned* probe     = (unsigned*)(ws + 285212672);

  // sentinel-fill hs (+hsF, probe when present)
  hipMemsetAsync(ws, 0xAA, FAST ? 268435456 : 134217728, stream);
  if (FAST) hipMemsetAsync(probe, 0xAA, 4096, stream);
  prep_ax<<<32768, 256, 0, stream>>>(pts, Ax);
  (void)hipFuncSetAttribute((const void*)lstm_coop,
                            hipFuncAttributeMaxDynamicSharedMemorySize, 163840);
  static int fastEn;
  fastEn = FAST;
  void* args[9];
  args[0] = (void*)&Whh; args[1] = (void*)&Wih; args[2] = (void*)&bih;
  args[3] = (void*)&bhh; args[4] = (void*)&Ax;  args[5] = (void*)&hs;
  args[6] = (void*)&hsF; args[7] = (void*)&probe; args[8] = (void*)&fastEn;
  hipLaunchCooperativeKernel((void*)lstm_coop, dim3(256), dim3(256), args, 163840, stream);
  head_kernel<<<8192, 256, 0, stream>>>(hs, Wlin, blin, out);
}

// Round 11
// 1454.047 us; speedup vs baseline: 4.3872x; 1.0764x over previous
//
#include <hip/hip_runtime.h>

// LSTM T=512 B=256 NP=34 H=512 NT=16.
// 16 groups (16 batches) x 16 blocks (32 h-cols, all 4 gates).
// FINAL = R8 (best measured: 1302 us kernel, passed):
//   * PIPELINED poll rounds: one inline-asm batch of 8 coherence-point loads
//     (sc0 sc1) + ONE s_waitcnt vmcnt(0), then 8 checks. (The serialized
//     per-load-waitcnt poll was the dominant cost: 8x ~900cy per round.)
//   * Ax prefetched one step ahead; x-MFMAs consumed at the END of the GEMM
//     so the cold-HBM x load never stalls the critical path.
//   * hs-only u64 publish (4 cols packed per storing lane), relaxed agent.
// Falsified directions (measured, do not revisit): same-XCD L2 fast path
// (R6/R7/R12: sc0 polls hit stale sentinel L2 lines forever; FETCH unchanged,
// pure overhead), release-counter handshake (R10: extra serial fence+hop),
// dual-group phase interleave (R9: poll-traffic congestion), counted-vmcnt
// staggered polls (R11: unsound when compiler emits spill VMEM),
// W-in-registers (R10/R11: spill pressure / stale-data hazard).
#define TT 512
#define BT 256
#define NP 34
#define HH 512
#define SENT 0xAAAAAAAAu

typedef short bf16x8 __attribute__((ext_vector_type(8)));
typedef float f32x4 __attribute__((ext_vector_type(4)));

static __device__ __forceinline__ unsigned short f2bf(float x) {
  unsigned int u = __float_as_uint(x);
  return (unsigned short)((u + 0x7fffu + ((u >> 16) & 1u)) >> 16);
}

template <int CTRL>
static __device__ __forceinline__ float dppq(float x) {
  return __int_as_float(
      __builtin_amdgcn_mov_dpp(__float_as_int(x), CTRL, 0xF, 0xF, true));
}

static __device__ __forceinline__ float rcpf(float x) {
  return __builtin_amdgcn_rcpf(x);
}

// One poll round: 8 pipelined coherence-point u64 loads, single waitcnt.
static __device__ __forceinline__ void load8_coh(const unsigned long long* p,
                                                 unsigned long long o[8]) {
  asm volatile(
      "global_load_dwordx2 %0, %8, off sc0 sc1\n\t"
      "global_load_dwordx2 %1, %9, off sc0 sc1\n\t"
      "global_load_dwordx2 %2, %10, off sc0 sc1\n\t"
      "global_load_dwordx2 %3, %11, off sc0 sc1\n\t"
      "global_load_dwordx2 %4, %12, off sc0 sc1\n\t"
      "global_load_dwordx2 %5, %13, off sc0 sc1\n\t"
      "global_load_dwordx2 %6, %14, off sc0 sc1\n\t"
      "global_load_dwordx2 %7, %15, off sc0 sc1\n\t"
      "s_waitcnt vmcnt(0)"
      : "=&v"(o[0]), "=&v"(o[1]), "=&v"(o[2]), "=&v"(o[3]),
        "=&v"(o[4]), "=&v"(o[5]), "=&v"(o[6]), "=&v"(o[7])
      : "v"(p), "v"(p + 256), "v"(p + 512), "v"(p + 768),
        "v"(p + 1024), "v"(p + 1280), "v"(p + 1536), "v"(p + 1792)
      : "memory");
}

// LDS (163840 B dynamic):
//   [0, 131072)        Whh slice bf16 [128 rows][512], 16B-chunk swizzle
//                      phys_chunk = c ^ (r&7). Row r = j*4 + q (j=col, q=gate).
//   [131072, 163840)   h-stage bf16 2 x [16][512] (same swizzle), double-buffered.
__global__ void __launch_bounds__(256, 1) lstm_coop(
    const float* __restrict__ Whh, const float* __restrict__ Wih,
    const float* __restrict__ bih, const float* __restrict__ bhh,
    const unsigned short* __restrict__ Ax,  // [T][256][64] bf16: [points(34),0..]
    unsigned short* hs)                     // [T][256][512] bf16, pre-set SENT
{
  extern __shared__ char smem[];
  unsigned short* Wl = (unsigned short*)smem;
  unsigned short* stg = (unsigned short*)(smem + 131072);

  const int tid = threadIdx.x;
  const int g = blockIdx.x & 15;   // group
  const int n = blockIdx.x >> 4;   // h-col slice [n*32, n*32+32)
  const int bbase = g * 16;

  // ---- init resident Whh slice (swizzled, reordered rows r = j*4+q) ----
  for (int idx = tid; idx < 128 * 512; idx += 256) {
    int r = idx >> 9, k = idx & 511;
    int grow = (r & 3) * 512 + n * 32 + (r >> 2);
    float v = Whh[(size_t)grow * 512 + k];
    int c = k >> 3;
    Wl[r * 512 + ((c ^ (r & 7)) << 3) + (k & 7)] = f2bf(v);
  }

  const int lane = tid & 63;
  const int w = tid >> 6;        // wave: owns cols [8w, 8w+8) of this slice
  const int m = lane & 15;       // A row (batch) / B tile-row
  const int ko = lane >> 4;      // k-subgroup
  const int r0 = 32 * w + m;
  const int q = m & 3;           // gate owned by this lane
  const int jj = m >> 2;         // col-in-wave quad group
  const int j0 = 8 * w + jj;     // acc0 col (block-local)
  const int j1 = j0 + 4;         // acc1 col
  const int mx = m & 7;

  // biases for all 4 gates at cols j0, j1
  float bi0[4], bi1[4];
#pragma unroll
  for (int gg = 0; gg < 4; ++gg) {
    int gr0 = gg * 512 + n * 32 + j0;
    int gr1 = gg * 512 + n * 32 + j1;
    bi0[gg] = bih[gr0] + bhh[gr0];
    bi1[gg] = bih[gr1] + bhh[gr1];
  }

  // hoisted x-slice W fragments (constant over t), straight from global Wih
  bf16x8 bx0a, bx1a, bx0b, bx1b;
  {
    int grow0 = q * 512 + n * 32 + j0;   // row r0    -> (gate q, col j0)
    int grow1 = q * 512 + n * 32 + j1;   // row r0+16 -> (gate q, col j1)
#pragma unroll
    for (int e = 0; e < 8; ++e) {
      int ka = 8 * ko + e;        // [0,32) always < 34
      int kb = 32 + 8 * ko + e;   // valid only while < 34
      bx0a[e] = (short)f2bf(Wih[grow0 * 34 + ka]);
      bx1a[e] = (short)f2bf(Wih[grow1 * 34 + ka]);
      bx0b[e] = (kb < NP) ? (short)f2bf(Wih[grow0 * 34 + kb]) : (short)0;
      bx1b[e] = (kb < NP) ? (short)f2bf(Wih[grow1 * 34 + kb]) : (short)0;
    }
  }
  __syncthreads();  // Wl ready (read-only hereafter)

  const bool q0 = (q == 0), q1 = (q == 1), q2 = (q == 2);
  float cc0 = 0.f, cc1 = 0.f;  // cell state for (batch 4ko+q, cols j0/j1)

  // prologue: x fragments for t=0
  bf16x8 xv0, xv1;
  {
    const unsigned short* xb = Ax + ((size_t)0 * BT + bbase + m) * 64;
    xv0 = *(const bf16x8*)(xb + (ko << 3));
    xv1 = *(const bf16x8*)(xb + 32 + (ko << 3));
  }

  for (int t = 0; t < TT; ++t) {
    // ---- acquire h(t-1): pipelined coherence-point poll rounds ----
    unsigned long long hv[8];
    if (t > 0) {
      const unsigned long long* pb =
          (const unsigned long long*)(hs + ((size_t)(t - 1) * BT + bbase) * HH) + tid;
      int guard = 0;
      for (;;) {
        load8_coh(pb, hv);
        unsigned ok = 1u;
#pragma unroll
        for (int u = 0; u < 8; ++u) {
          unsigned long long x = hv[u];
          ok &= ((unsigned)x != SENT) & ((unsigned)(x >> 32) != SENT) ? 1u : 0u;
        }
        if (ok) break;
        if (++guard > (1 << 18)) break;  // deadlock guard
      }
    } else {
#pragma unroll
      for (int u = 0; u < 8; ++u) hv[u] = 0ull;
    }

    // prefetch next step's x fragments (consumed at END of next GEMM,
    // ~a full step away -> latency fully hidden)
    bf16x8 xn0, xn1;
    {
      int tn = (t + 1 < TT) ? t + 1 : t;
      const unsigned short* xb = Ax + ((size_t)tn * BT + bbase + m) * 64;
      xn0 = *(const bf16x8*)(xb + (ko << 3));
      xn1 = *(const bf16x8*)(xb + 32 + (ko << 3));
    }

    // stage into LDS (swizzled), double-buffered by t parity
    unsigned short* st = stg + (t & 1) * 8192;
#pragma unroll
    for (int u = 0; u < 8; ++u) {
      int idx = u * 256 + tid;           // [0,2048) 8B units
      int mm = idx >> 7, cu = idx & 127; // row, 8B unit in row
      int c16 = cu >> 1, half = cu & 1;
      *(unsigned long long*)&st[mm * 512 + ((c16 ^ (mm & 7)) << 3) + (half << 2)] = hv[u];
    }
    __syncthreads();  // the only per-step barrier: stage visible

    // ---- gates GEMM: h (K=512) then x (K=64) at the end, 4 acc chains ----
    f32x4 a0a = {0.f, 0.f, 0.f, 0.f}, a0b = {0.f, 0.f, 0.f, 0.f};
    f32x4 a1a = {0.f, 0.f, 0.f, 0.f}, a1b = {0.f, 0.f, 0.f, 0.f};
#pragma unroll
    for (int s = 0; s < 16; ++s) {
      int cs = (((4 * s + ko) ^ mx) << 3);
      bf16x8 av = *(const bf16x8*)&st[m * 512 + cs];
      bf16x8 bv0 = *(const bf16x8*)&Wl[r0 * 512 + cs];
      bf16x8 bv1 = *(const bf16x8*)&Wl[(r0 + 16) * 512 + cs];
      if (s & 1) {
        a0b = __builtin_amdgcn_mfma_f32_16x16x32_bf16(av, bv0, a0b, 0, 0, 0);
        a1b = __builtin_amdgcn_mfma_f32_16x16x32_bf16(av, bv1, a1b, 0, 0, 0);
      } else {
        a0a = __builtin_amdgcn_mfma_f32_16x16x32_bf16(av, bv0, a0a, 0, 0, 0);
        a1a = __builtin_amdgcn_mfma_f32_16x16x32_bf16(av, bv1, a1a, 0, 0, 0);
      }
    }
    a0a = __builtin_amdgcn_mfma_f32_16x16x32_bf16(xv0, bx0a, a0a, 0, 0, 0);
    a1a = __builtin_amdgcn_mfma_f32_16x16x32_bf16(xv0, bx1a, a1a, 0, 0, 0);
    a0b = __builtin_amdgcn_mfma_f32_16x16x32_bf16(xv1, bx0b, a0b, 0, 0, 0);
    a1b = __builtin_amdgcn_mfma_f32_16x16x32_bf16(xv1, bx1b, a1b, 0, 0, 0);
    f32x4 A0 = a0a + a0b;
    f32x4 A1 = a1a + a1b;

    // ---- epilogue: quad gather (rot d brings lane(q+d)'s A[q]) ----
    // D layout: col = lane&15 -> (q,jj); row = 4ko+reg -> batch. Lane q owns
    // reg q: cell (batch 4ko+q, col j). send_d = A[(q-d)&3].
    float own0 = q0 ? A0.x : q1 ? A0.y : q2 ? A0.z : A0.w;
    float t1s0 = q0 ? A0.w : q1 ? A0.x : q2 ? A0.y : A0.z;
    float t2s0 = q0 ? A0.z : q1 ? A0.w : q2 ? A0.x : A0.y;
    float t3s0 = q0 ? A0.y : q1 ? A0.z : q2 ? A0.w : A0.x;
    float r1_0 = dppq<0x39>(t1s0);  // quad rot +1
    float r2_0 = dppq<0x4E>(t2s0);  // quad rot +2
    float r3_0 = dppq<0x93>(t3s0);  // quad rot +3
    float own1 = q0 ? A1.x : q1 ? A1.y : q2 ? A1.z : A1.w;
    float t1s1 = q0 ? A1.w : q1 ? A1.x : q2 ? A1.y : A1.z;
    float t2s1 = q0 ? A1.z : q1 ? A1.w : q2 ? A1.x : A1.y;
    float t3s1 = q0 ? A1.y : q1 ? A1.z : q2 ? A1.w : A1.x;
    float r1_1 = dppq<0x39>(t1s1);
    float r2_1 = dppq<0x4E>(t2s1);
    float r3_1 = dppq<0x93>(t3s1);
    float gi0 = (q0 ? own0 : q1 ? r3_0 : q2 ? r2_0 : r1_0) + bi0[0];
    float gf0 = (q0 ? r1_0 : q1 ? own0 : q2 ? r3_0 : r2_0) + bi0[1];
    float gg0 = (q0 ? r2_0 : q1 ? r1_0 : q2 ? own0 : r3_0) + bi0[2];
    float go0 = (q0 ? r3_0 : q1 ? r2_0 : q2 ? r1_0 : own0) + bi0[3];
    float gi1 = (q0 ? own1 : q1 ? r3_1 : q2 ? r2_1 : r1_1) + bi1[0];
    float gf1 = (q0 ? r1_1 : q1 ? own1 : q2 ? r3_1 : r2_1) + bi1[1];
    float gg1 = (q0 ? r2_1 : q1 ? r1_1 : q2 ? own1 : r3_1) + bi1[2];
    float go1 = (q0 ? r3_1 : q1 ? r2_1 : q2 ? r1_1 : own1) + bi1[3];

    float ii0 = rcpf(1.f + __expf(-gi0));
    float ff0 = rcpf(1.f + __expf(-gf0));
    float tg0 = 2.f * rcpf(1.f + __expf(-2.f * gg0)) - 1.f;
    float oo0 = rcpf(1.f + __expf(-go0));
    cc0 = ff0 * cc0 + ii0 * tg0;
    float h0 = oo0 * (2.f * rcpf(1.f + __expf(-2.f * cc0)) - 1.f);

    float ii1 = rcpf(1.f + __expf(-gi1));
    float ff1 = rcpf(1.f + __expf(-gf1));
    float tg1 = 2.f * rcpf(1.f + __expf(-2.f * gg1)) - 1.f;
    float oo1 = rcpf(1.f + __expf(-go1));
    cc1 = ff1 * cc1 + ii1 * tg1;
    float h1 = oo1 * (2.f * rcpf(1.f + __expf(-2.f * cc1)) - 1.f);

    // pack 4 consecutive cols into one u64 per storing lane:
    // xor-4 pairs cols (j, j+1); xor-8 merges quad-pairs into (8w..8w+3)
    // at jj=0 and (8w+4..8w+7) at jj=2. Single agent-scope u64 publish.
    float h0p = __shfl_xor(h0, 4);
    float h1p = __shfl_xor(h1, 4);
    unsigned p0 = (unsigned)f2bf(h0) | ((unsigned)f2bf(h0p) << 16);
    unsigned p1 = (unsigned)f2bf(h1) | ((unsigned)f2bf(h1p) << 16);
    unsigned s0 = (unsigned)__shfl_xor((int)p0, 8);
    unsigned s1 = (unsigned)__shfl_xor((int)p1, 8);
    if (!(jj & 1)) {
      unsigned long long val = (jj == 0)
          ? (((unsigned long long)s0 << 32) | p0)    // cols 8w..8w+3
          : (((unsigned long long)p1 << 32) | s1);   // cols 8w+4..8w+7
      size_t uidx = ((size_t)t * BT + bbase + 4 * ko + q) * 128 +
                    8 * n + 2 * w + (jj >> 1);
      __hip_atomic_store((unsigned long long*)hs + uidx, val,
                         __ATOMIC_RELAXED, __HIP_MEMORY_SCOPE_AGENT);
    }
    xv0 = xn0;
    xv1 = xn1;
  }
}

// Ax[t][b][k] = bf16(points[t][b][k]) for k<34 else 0
__global__ void __launch_bounds__(256) prep_ax(const float* __restrict__ pts,
                                               unsigned short* __restrict__ Ax) {
  size_t i = (size_t)blockIdx.x * 256 + threadIdx.x;  // [0, 512*256*64)
  int k = (int)(i & 63);
  size_t tb = i >> 6;
  float v = (k < NP) ? pts[tb * NP + k] : 0.f;
  Ax[i] = f2bf(v);
}

// logits = hs @ W_lin^T + b_lin ; softmax over 16
__global__ void __launch_bounds__(256) head_kernel(const unsigned short* __restrict__ hs,
                                                   const float* __restrict__ Wlin,
                                                   const float* __restrict__ blin,
                                                   float* __restrict__ out) {
  __shared__ float wl[16 * 513];
  __shared__ float bl[16];
  __shared__ unsigned short hl[16 * 520];
  const int tid = threadIdx.x;
  for (int i = tid; i < 16 * 512; i += 256) wl[(i >> 9) * 513 + (i & 511)] = Wlin[i];
  if (tid < 16) bl[tid] = blin[tid];
  const size_t Rb = (size_t)blockIdx.x * 16;  // 16 rows of [131072][512]
  const uint4* gsrc = (const uint4*)(hs + Rb * 512);
#pragma unroll
  for (int j = 0; j < 4; ++j) {
    int e8 = tid + 256 * j;  // uint4 index, 8 bf16 each
    uint4 v = gsrc[e8];
    int r = e8 >> 6, k = (e8 & 63) << 3;
    *(uint4*)&hl[r * 520 + k] = v;
  }
  __syncthreads();
  const int r = tid >> 4, tg = tid & 15;
  float acc = bl[tg];
  const float* wp = &wl[tg * 513];
#pragma unroll 4
  for (int k8 = 0; k8 < 64; ++k8) {
    uint4 hv = *(const uint4*)&hl[r * 520 + (k8 << 3)];
    const float* w8 = wp + (k8 << 3);
    acc += __uint_as_float(hv.x << 16) * w8[0];
    acc += __uint_as_float(hv.x & 0xffff0000u) * w8[1];
    acc += __uint_as_float(hv.y << 16) * w8[2];
    acc += __uint_as_float(hv.y & 0xffff0000u) * w8[3];
    acc += __uint_as_float(hv.z << 16) * w8[4];
    acc += __uint_as_float(hv.z & 0xffff0000u) * w8[5];
    acc += __uint_as_float(hv.w << 16) * w8[6];
    acc += __uint_as_float(hv.w & 0xffff0000u) * w8[7];
  }
  float mx = acc;
#pragma unroll
  for (int d = 8; d; d >>= 1) mx = fmaxf(mx, __shfl_xor(mx, d, 16));
  float e = __expf(acc - mx);
  float sm = e;
#pragma unroll
  for (int d = 8; d; d >>= 1) sm += __shfl_xor(sm, d, 16);
  out[Rb * 16 + tid] = e / sm;
}

extern "C" void kernel_launch(void* const* d_in, const int* in_sizes, int n_in,
                              void* d_out, int out_size, void* d_ws, size_t ws_size,
                              hipStream_t stream) {
  (void)in_sizes; (void)n_in; (void)out_size; (void)ws_size;
  const float* pts  = (const float*)d_in[0];
  const float* Wih  = (const float*)d_in[1];
  const float* Whh  = (const float*)d_in[2];
  const float* bih  = (const float*)d_in[3];
  const float* bhh  = (const float*)d_in[4];
  const float* Wlin = (const float*)d_in[5];
  const float* blin = (const float*)d_in[6];
  float* out = (float*)d_out;
  char* ws = (char*)d_ws;
  // ws layout: hs 134217728 B | Ax 16777216 B
  unsigned short* hs = (unsigned short*)ws;
  unsigned short* Ax = (unsigned short*)(ws + 134217728);

  // sentinel-fill hs (self-validating exchange protocol needs every launch)
  hipMemsetAsync(hs, 0xAA, 134217728, stream);
  prep_ax<<<32768, 256, 0, stream>>>(pts, Ax);
  (void)hipFuncSetAttribute((const void*)lstm_coop,
                            hipFuncAttributeMaxDynamicSharedMemorySize, 163840);
  void* args[6];
  args[0] = (void*)&Whh; args[1] = (void*)&Wih; args[2] = (void*)&bih;
  args[3] = (void*)&bhh; args[4] = (void*)&Ax;  args[5] = (void*)&hs;
  hipLaunchCooperativeKernel((void*)lstm_coop, dim3(256), dim3(256), args, 163840, stream);
  head_kernel<<<8192, 256, 0, stream>>>(hs, Wlin, blin, out);
}